// Round 1
// 192.525 us; speedup vs baseline: 1.2227x; 1.2227x over previous
//
#include <hip/hip_runtime.h>

typedef unsigned short u16;
typedef __bf16 bf16x8 __attribute__((ext_vector_type(8)));
typedef float f32x4 __attribute__((ext_vector_type(4)));
typedef unsigned short u16x8 __attribute__((ext_vector_type(8)));

#define F_FACES 65536
#define N_FACES 131072
#define C_CH 128
// ws layout (bytes):
//   [0,256)        zeropage (zeros; masked-gather target)
//   [256,3328)     W2 folded fp32  [b][o][i]  (768 floats)
//   [3328,4352)    styles1 fp32    [b][i]     (256 floats)
//   [4352,5376)    styles2 fp32    [b][i]     (256 floats)
//   [5376,595200)  W1 folded bf16, FRAGMENT layout [b][k][chunk16][o128][j8]
//   [595200, +16777216) const bf16 copy [F][C]
#define WS_W2F 256
#define WS_S1 3328
#define WS_S2 4352
#define WS_W1 5376
#define WS_CONST 595200
#define XELEMS 16777216  // N_FACES*128

__device__ inline u16 f2bf(float f) {
    unsigned u = __builtin_bit_cast(unsigned, f);
    unsigned r = (u + 0x7fffu + ((u >> 16) & 1u)) >> 16;
    return (u16)r;
}

__device__ inline void gl_lds16(const void* g, void* l) {
    __builtin_amdgcn_global_load_lds(
        (const __attribute__((address_space(1))) void*)g,
        (__attribute__((address_space(3))) void*)l, 16, 0, 0);
}

// ---------------- kernel 0a: styles1+styles2, one wave per 512-dot ----------------
__global__ __launch_bounds__(256) void k0a_styles(
    const float* __restrict__ wsv, const float* __restrict__ a1W, const float* __restrict__ a1b,
    const float* __restrict__ a2W, const float* __restrict__ a2b, unsigned char* __restrict__ wsb)
{
    int wv = threadIdx.x >> 6, lane = threadIdx.x & 63;
    int c = blockIdx.x * 4 + wv;
    int which = c >> 8, rem = c & 255, b = rem >> 7, o = rem & 127;
    const float* W = (which ? a2W : a1W) + o * 512 + lane * 8;
    const float* x = wsv + (b * 2 + which) * 512 + lane * 8;
    float4 wa = *(const float4*)(W);
    float4 wb = *(const float4*)(W + 4);
    float4 xa = *(const float4*)(x);
    float4 xb = *(const float4*)(x + 4);
    float s = wa.x * xa.x + wa.y * xa.y + wa.z * xa.z + wa.w * xa.w
            + wb.x * xb.x + wb.y * xb.y + wb.z * xb.z + wb.w * xb.w;
#pragma unroll
    for (int d = 1; d < 64; d <<= 1) s += __shfl_xor(s, d);
    if (lane == 0) {
        const float g512 = 0.04419417382415922f;   // 1/sqrt(512)
        const float g128 = 0.08838834764831845f;   // 1/sqrt(128)
        float* wsf = (float*)wsb;
        if (which == 0) {
            wsf[WS_S1 / 4 + b * 128 + o] = s * g512 + a1b[o];
        } else {
            wsf[WS_S2 / 4 + b * 128 + o] = (s * g512 + a2b[o]) * g128;
        }
    }
}

// ---------------- kernel 0f: fused {const cvt | W1 demod+fold | W2 fold+zeropage} ----
// blocks [0,4096): fp32->bf16 const copy
// blocks [4096,4352): per-(b,o) demod + fold of W1 into fragment layout (256 thr)
// block 4352: zeropage + W2 fold
__global__ __launch_bounds__(256) void k0f_fused(
    const float* __restrict__ cst, const float* __restrict__ w1g,
    const float* __restrict__ w2, unsigned char* __restrict__ wsb)
{
    __shared__ float red[4];
    int bid = blockIdx.x;
    int tid = threadIdx.x;

    if (bid < 4096) {
        u16* dst = (u16*)(wsb + WS_CONST);
        int base = (bid * 256 + tid) * 8;
        float4 a = *(const float4*)(cst + base);
        float4 c = *(const float4*)(cst + base + 4);
        u16x8 p;
        p[0] = f2bf(a.x); p[1] = f2bf(a.y); p[2] = f2bf(a.z); p[3] = f2bf(a.w);
        p[4] = f2bf(c.x); p[5] = f2bf(c.y); p[6] = f2bf(c.z); p[7] = f2bf(c.w);
        *(u16x8*)(dst + base) = p;
        return;
    }
    if (bid < 4352) {
        int bo = bid - 4096;
        int b = bo >> 7, o = bo & 127;
        const float* s1 = (const float*)(wsb + WS_S1) + b * 128;
        float sum = 0.f;
        for (int e = tid; e < 1152; e += 256) {
            int i = e / 9;
            float w = w1g[o * 1152 + e] * s1[i];
            sum += w * w;
        }
        int wv = tid >> 6, lane = tid & 63;
#pragma unroll
        for (int d = 1; d < 64; d <<= 1) sum += __shfl_xor(sum, d);
        if (lane == 0) red[wv] = sum;
        __syncthreads();
        float dm = rsqrtf(red[0] + red[1] + red[2] + red[3] + 1e-8f);
        u16* w1out = (u16*)(wsb + WS_W1);
        for (int wd = tid; wd < 576; wd += 256) {
            int k = wd >> 6;
            int ii = (wd & 63) * 2;
            float v0 = w1g[(o * 128 + ii) * 9 + k] * s1[ii] * dm;
            float v1 = w1g[(o * 128 + ii + 1) * 9 + k] * s1[ii + 1] * dm;
            unsigned pack = (unsigned)f2bf(v0) | ((unsigned)f2bf(v1) << 16);
            *(unsigned*)&w1out[(size_t)((((b * 9 + k) * 16 + (ii >> 3)) * 128 + o) * 8 + (ii & 7))] = pack;
        }
        return;
    }
    // bid == 4352: zeropage + W2 fold
    float* wsf = (float*)wsb;
    if (tid < 64) wsf[tid] = 0.f;
#pragma unroll
    for (int r = 0; r < 3; ++r) {
        int id = tid + r * 256;  // < 768
        int b2 = id / 384;
        int rem = id - b2 * 384;
        int o2 = rem >> 7;
        int i = rem & 127;
        wsf[WS_W2F / 4 + id] = w2[o2 * 128 + i] * wsf[WS_S2 / 4 + b2 * 128 + i];
    }
}

// ---------------- kernel 1: gathered GEMM conv1, double-buffered + counted vmcnt ----
// 512 threads (8 waves, 2M x 4N), 128x128 tile, LDS 2x32KB, 2 blocks/CU.
// Per k: [issue 8 B-loads] [issue 4 gl_lds for k+1] [prefetch idx k+2]
//        [vmcnt(counted, never 0 mid-loop)] [raw barrier] [32 MFMA] [raw barrier]
__global__ __launch_bounds__(512, 4) void k1_conv(
    const int* __restrict__ neigh, const int* __restrict__ ispad,
    const float* __restrict__ noise_c, const float* __restrict__ nstr,
    const float* __restrict__ bias1, const unsigned char* __restrict__ wsb,
    float* __restrict__ out)
{
    __shared__ __align__(16) u16 As[2][128 * 128];  // 64KB double buffer, XOR-16 swizzled

    const int tid = threadIdx.x;
    const int wv = tid >> 6, lane = tid & 63;
    const int quad = lane >> 4, l15 = lane & 15;
    const int f0 = blockIdx.x * 128;
    const int b = f0 >> 16;
    const u16* cst = (const u16*)(wsb + WS_CONST);
    const u16* w1ws = (const u16*)(wsb + WS_W1) + (size_t)b * 147456;  // 9*16*128*8
    const char* zp = (const char*)wsb;
    const int wm = wv & 1, wn = wv >> 1;

    f32x4 acc[4][2] = {};
    int ia[4], ip[4];

    // ---- prologue: idx(0), stage tile0 -> buf0, idx(1) ----
#pragma unroll
    for (int r = 0; r < 4; ++r) {
        int nb = (f0 + (wv * 4 + r) * 4 + quad) * 9 + 0;
        ia[r] = neigh[nb]; ip[r] = ispad[nb];
    }
#pragma unroll
    for (int r = 0; r < 4; ++r) {
        int row = (wv * 4 + r) * 4 + quad;
        bool valid = (ip[r] == 0) && ((unsigned)ia[r] < 131072u);
        const char* src = valid ? (const char*)(cst + ((size_t)(ia[r] & 65535) << 7)) : zp;
        gl_lds16(src + ((l15 ^ (row & 15)) << 4), (char*)(&As[0][0]) + ((wv * 4 + r) << 10));
    }
#pragma unroll
    for (int r = 0; r < 4; ++r) {
        int nb = (f0 + (wv * 4 + r) * 4 + quad) * 9 + 1;
        ia[r] = neigh[nb]; ip[r] = ispad[nb];
    }

#pragma unroll
    for (int k = 0; k < 9; ++k) {
        // B fragments for this k — issued FIRST so consuming them in compute
        // does not FIFO-drain the k+1 gather prefetch.
        bf16x8 bfr[4][2];
#pragma unroll
        for (int s = 0; s < 4; ++s)
#pragma unroll
            for (int nt = 0; nt < 2; ++nt)
                bfr[s][nt] = *reinterpret_cast<const bf16x8*>(
                    w1ws + (((k * 16 + s * 4 + quad) * 128) + wn * 32 + nt * 16 + l15) * 8);
        asm volatile("" ::: "memory");
        __builtin_amdgcn_sched_barrier(0);

        // stage tile k+1 (gather, masked -> zeropage), swizzled source
        if (k < 8) {
#pragma unroll
            for (int r = 0; r < 4; ++r) {
                int row = (wv * 4 + r) * 4 + quad;
                bool valid = (ip[r] == 0) && ((unsigned)ia[r] < 131072u);
                const char* src = valid ? (const char*)(cst + ((size_t)(ia[r] & 65535) << 7)) : zp;
                gl_lds16(src + ((l15 ^ (row & 15)) << 4),
                         (char*)(&As[(k + 1) & 1][0]) + ((wv * 4 + r) << 10));
            }
        }
        // prefetch neighbor indices for tile k+2 (consumed next iteration -> wait is free)
        if (k < 7) {
#pragma unroll
            for (int r = 0; r < 4; ++r) {
                int nb = (f0 + (wv * 4 + r) * 4 + quad) * 9 + (k + 2);
                ia[r] = neigh[nb]; ip[r] = ispad[nb];
            }
        }
        // counted vmcnt: N = ops issued after tile-k's gathers (8 B + 4 gl_lds + 8 idx)
        if (k < 7)       asm volatile("s_waitcnt vmcnt(20)" ::: "memory");
        else if (k == 7) asm volatile("s_waitcnt vmcnt(12)" ::: "memory");
        else             asm volatile("s_waitcnt vmcnt(8)" ::: "memory");
        __builtin_amdgcn_s_barrier();
        __builtin_amdgcn_sched_barrier(0);

        // compute on As[k&1]
        const u16* Ab = &As[k & 1][0];
#pragma unroll
        for (int s = 0; s < 4; ++s) {
            bf16x8 af[4];
#pragma unroll
            for (int mt = 0; mt < 4; ++mt) {
                int face = wm * 64 + mt * 16 + l15;
                int chunk = (s * 4 + quad) ^ l15;
                af[mt] = *reinterpret_cast<const bf16x8*>(&Ab[face * 128 + chunk * 8]);
            }
#pragma unroll
            for (int mt = 0; mt < 4; ++mt)
#pragma unroll
                for (int nt = 0; nt < 2; ++nt)
                    acc[mt][nt] = __builtin_amdgcn_mfma_f32_16x16x32_bf16(
                        af[mt], bfr[s][nt], acc[mt][nt], 0, 0, 0);
        }
        asm volatile("s_waitcnt lgkmcnt(0)" ::: "memory");
        __builtin_amdgcn_s_barrier();
        __builtin_amdgcn_sched_barrier(0);
    }

    // epilogue: + noise + bias1, lrelu(0.2)*sqrt(2), clip +-256, fp32 store
    float ns = nstr[0];
    float b1v[2];
    b1v[0] = bias1[wn * 32 + l15];
    b1v[1] = bias1[wn * 32 + 16 + l15];
#pragma unroll
    for (int mt = 0; mt < 4; ++mt) {
#pragma unroll
        for (int r = 0; r < 4; ++r) {
            int face = f0 + wm * 64 + mt * 16 + quad * 4 + r;
            float nz = noise_c[face & 65535] * ns;
#pragma unroll
            for (int nt = 0; nt < 2; ++nt) {
                float v = acc[mt][nt][r] + nz + b1v[nt];
                v = (v > 0.f) ? v : 0.2f * v;
                v *= 1.41421356f;
                v = fminf(fmaxf(v, -256.f), 256.f);
                out[(size_t)face * 128 + wn * 32 + nt * 16 + l15] = v;
            }
        }
    }
}

// ---------------- kernel 2: conv2 (k=1 gather) + bias + clip ----------------
__global__ __launch_bounds__(256) void k2_img(
    const int* __restrict__ neigh, const int* __restrict__ ispad,
    const float* __restrict__ w2f, const float* __restrict__ bias2,
    const float* __restrict__ xbuf, float* __restrict__ imgout)
{
    __shared__ float ws2[768];
    int tid = threadIdx.x;
    ws2[tid] = w2f[tid];
    ws2[tid + 256] = w2f[tid + 256];
    ws2[tid + 512] = w2f[tid + 512];
    __syncthreads();
    int wv = tid >> 6, lane = tid & 63;
    int g = lane >> 4, sub = lane & 15;
    int face = blockIdx.x * 16 + wv * 4 + g;
    int b = face >> 16;
    int idx = neigh[face * 9];
    bool valid = (ispad[face * 9] == 0) && ((unsigned)idx < 131072u);
    float a0 = 0.f, a1 = 0.f, a2 = 0.f;
    if (valid) {
        float4 d0 = *(const float4*)(xbuf + (size_t)idx * 128 + sub * 8);
        float4 d1 = *(const float4*)(xbuf + (size_t)idx * 128 + sub * 8 + 4);
        float f[8] = {d0.x, d0.y, d0.z, d0.w, d1.x, d1.y, d1.z, d1.w};
        const float* w0 = &ws2[(b * 3 + 0) * 128 + sub * 8];
        const float* w1 = &ws2[(b * 3 + 1) * 128 + sub * 8];
        const float* w2p = &ws2[(b * 3 + 2) * 128 + sub * 8];
#pragma unroll
        for (int j = 0; j < 8; ++j) {
            a0 += f[j] * w0[j];
            a1 += f[j] * w1[j];
            a2 += f[j] * w2p[j];
        }
    }
#pragma unroll
    for (int d = 1; d < 16; d <<= 1) {
        a0 += __shfl_xor(a0, d);
        a1 += __shfl_xor(a1, d);
        a2 += __shfl_xor(a2, d);
    }
    if (sub < 3) {
        float v = (sub == 0) ? a0 : (sub == 1) ? a1 : a2;
        v += bias2[sub];
        v = fminf(fmaxf(v, -256.f), 256.f);
        imgout[face * 3 + sub] = v;
    }
}

extern "C" void kernel_launch(void* const* d_in, const int* in_sizes, int n_in,
                              void* d_out, int out_size, void* d_ws, size_t ws_size,
                              hipStream_t stream) {
    const int* neigh = (const int*)d_in[0];
    const int* ispad = (const int*)d_in[1];
    const float* wsv = (const float*)d_in[2];
    const float* cst = (const float*)d_in[3];
    const float* a1W = (const float*)d_in[4];
    const float* a1b = (const float*)d_in[5];
    const float* w1g = (const float*)d_in[6];
    const float* noise_c = (const float*)d_in[7];
    const float* nstr = (const float*)d_in[8];
    const float* bias1 = (const float*)d_in[9];
    const float* a2W = (const float*)d_in[10];
    const float* a2b = (const float*)d_in[11];
    const float* w2 = (const float*)d_in[12];
    const float* bias2 = (const float*)d_in[13];
    float* out = (float*)d_out;
    unsigned char* wsb = (unsigned char*)d_ws;

    k0a_styles<<<128, 256, 0, stream>>>(wsv, a1W, a1b, a2W, a2b, wsb);
    k0f_fused<<<4353, 256, 0, stream>>>(cst, w1g, w2, wsb);
    k1_conv<<<1024, 512, 0, stream>>>(neigh, ispad, noise_c, nstr, bias1, wsb, out);
    k2_img<<<8192, 256, 0, stream>>>(neigh, ispad, (const float*)(wsb + WS_W2F), bias2,
                                     out, out + XELEMS);
}

// Round 2
// 190.863 us; speedup vs baseline: 1.2334x; 1.0087x over previous
//
#include <hip/hip_runtime.h>

typedef unsigned short u16;
typedef __bf16 bf16x8 __attribute__((ext_vector_type(8)));
typedef float f32x4 __attribute__((ext_vector_type(4)));
typedef unsigned short u16x8 __attribute__((ext_vector_type(8)));

#define F_FACES 65536
#define N_FACES 131072
#define C_CH 128
// ws layout (bytes):
//   [0,256)        zeropage (zeros; masked-gather target)
//   [256,3328)     W2 folded fp32  [b][o][i]  (768 floats)
//   [3328,4352)    styles1 fp32    [b][i]     (256 floats)
//   [4352,5376)    styles2 fp32    [b][i]     (256 floats)
//   [5376,595200)  W1 folded bf16, FRAGMENT layout [b][k][chunk16][o128][j8]
//   [595200, +16777216) const bf16 copy [F][C]
#define WS_W2F 256
#define WS_S1 3328
#define WS_S2 4352
#define WS_W1 5376
#define WS_CONST 595200
#define XELEMS 16777216  // N_FACES*128

__device__ inline u16 f2bf(float f) {
    unsigned u = __builtin_bit_cast(unsigned, f);
    unsigned r = (u + 0x7fffu + ((u >> 16) & 1u)) >> 16;
    return (u16)r;
}

__device__ inline void gl_lds16(const void* g, void* l) {
    __builtin_amdgcn_global_load_lds(
        (const __attribute__((address_space(1))) void*)g,
        (__attribute__((address_space(3))) void*)l, 16, 0, 0);
}

// ---------------- kernel 0a: styles1+styles2, one wave per 512-dot ----------------
__global__ __launch_bounds__(256) void k0a_styles(
    const float* __restrict__ wsv, const float* __restrict__ a1W, const float* __restrict__ a1b,
    const float* __restrict__ a2W, const float* __restrict__ a2b, unsigned char* __restrict__ wsb)
{
    int wv = threadIdx.x >> 6, lane = threadIdx.x & 63;
    int c = blockIdx.x * 4 + wv;
    int which = c >> 8, rem = c & 255, b = rem >> 7, o = rem & 127;
    const float* W = (which ? a2W : a1W) + o * 512 + lane * 8;
    const float* x = wsv + (b * 2 + which) * 512 + lane * 8;
    float4 wa = *(const float4*)(W);
    float4 wb = *(const float4*)(W + 4);
    float4 xa = *(const float4*)(x);
    float4 xb = *(const float4*)(x + 4);
    float s = wa.x * xa.x + wa.y * xa.y + wa.z * xa.z + wa.w * xa.w
            + wb.x * xb.x + wb.y * xb.y + wb.z * xb.z + wb.w * xb.w;
#pragma unroll
    for (int d = 1; d < 64; d <<= 1) s += __shfl_xor(s, d);
    if (lane == 0) {
        const float g512 = 0.04419417382415922f;   // 1/sqrt(512)
        const float g128 = 0.08838834764831845f;   // 1/sqrt(128)
        float* wsf = (float*)wsb;
        if (which == 0) {
            wsf[WS_S1 / 4 + b * 128 + o] = s * g512 + a1b[o];
        } else {
            wsf[WS_S2 / 4 + b * 128 + o] = (s * g512 + a2b[o]) * g128;
        }
    }
}

// ---------------- kernel 0f: fused {W1 demod+fold | W2 fold+zeropage | const cvt} ----
// blocks [0,256): per-(b,o) demod + fold of W1 (latency-bound -> dispatched FIRST
//                 so they overlap under the cvt wave instead of tailing)
// block 256: zeropage + W2 fold
// blocks [257,4353): fp32->bf16 const copy
__global__ __launch_bounds__(256) void k0f_fused(
    const float* __restrict__ cst, const float* __restrict__ w1g,
    const float* __restrict__ w2, unsigned char* __restrict__ wsb)
{
    __shared__ float red[4];
    int bid = blockIdx.x;
    int tid = threadIdx.x;

    if (bid >= 257) {
        u16* dst = (u16*)(wsb + WS_CONST);
        int base = ((bid - 257) * 256 + tid) * 8;
        float4 a = *(const float4*)(cst + base);
        float4 c = *(const float4*)(cst + base + 4);
        u16x8 p;
        p[0] = f2bf(a.x); p[1] = f2bf(a.y); p[2] = f2bf(a.z); p[3] = f2bf(a.w);
        p[4] = f2bf(c.x); p[5] = f2bf(c.y); p[6] = f2bf(c.z); p[7] = f2bf(c.w);
        *(u16x8*)(dst + base) = p;
        return;
    }
    if (bid < 256) {
        int bo = bid;
        int b = bo >> 7, o = bo & 127;
        const float* s1 = (const float*)(wsb + WS_S1) + b * 128;
        float sum = 0.f;
        for (int e = tid; e < 1152; e += 256) {
            int i = e / 9;
            float w = w1g[o * 1152 + e] * s1[i];
            sum += w * w;
        }
        int wv = tid >> 6, lane = tid & 63;
#pragma unroll
        for (int d = 1; d < 64; d <<= 1) sum += __shfl_xor(sum, d);
        if (lane == 0) red[wv] = sum;
        __syncthreads();
        float dm = rsqrtf(red[0] + red[1] + red[2] + red[3] + 1e-8f);
        u16* w1out = (u16*)(wsb + WS_W1);
        for (int wd = tid; wd < 576; wd += 256) {
            int k = wd >> 6;
            int ii = (wd & 63) * 2;
            float v0 = w1g[(o * 128 + ii) * 9 + k] * s1[ii] * dm;
            float v1 = w1g[(o * 128 + ii + 1) * 9 + k] * s1[ii + 1] * dm;
            unsigned pack = (unsigned)f2bf(v0) | ((unsigned)f2bf(v1) << 16);
            *(unsigned*)&w1out[(size_t)((((b * 9 + k) * 16 + (ii >> 3)) * 128 + o) * 8 + (ii & 7))] = pack;
        }
        return;
    }
    // bid == 256: zeropage + W2 fold
    float* wsf = (float*)wsb;
    if (tid < 64) wsf[tid] = 0.f;
#pragma unroll
    for (int r = 0; r < 3; ++r) {
        int id = tid + r * 256;  // < 768
        int b2 = id / 384;
        int rem = id - b2 * 384;
        int o2 = rem >> 7;
        int i = rem & 127;
        wsf[WS_W2F / 4 + id] = w2[o2 * 128 + i] * wsf[WS_S2 / 4 + b2 * 128 + i];
    }
}

// ---------------- kernel 1: gathered GEMM conv1, double-buffered + counted vmcnt ----
// 256 threads (4 waves), 64x128 tile, LDS 2x16KB -> 5 blocks/CU (160KB exactly).
// Small barrier domains: a straggling gather stalls 4 waves, not 16; 5 independent
// block phases per CU interleave. Per-wave structure identical to previous version:
// per k: [8 B-loads] [4 gl_lds k+1] [8 idx loads k+2] [counted vmcnt] [bar] [32 MFMA] [bar]
__global__ __launch_bounds__(256, 5) void k1_conv(
    const int* __restrict__ neigh, const int* __restrict__ ispad,
    const float* __restrict__ noise_c, const float* __restrict__ nstr,
    const float* __restrict__ bias1, const unsigned char* __restrict__ wsb,
    float* __restrict__ out)
{
    __shared__ __align__(16) u16 As[2][64 * 128];  // 2x16KB double buffer, XOR-16 swizzled

    const int tid = threadIdx.x;
    const int wv = tid >> 6, lane = tid & 63;
    const int quad = lane >> 4, l15 = lane & 15;
    const int f0 = blockIdx.x * 64;
    const int b = f0 >> 16;
    const u16* cst = (const u16*)(wsb + WS_CONST);
    const u16* w1ws = (const u16*)(wsb + WS_W1) + (size_t)b * 147456;  // 9*16*128*8
    const char* zp = (const char*)wsb;

    f32x4 acc[4][2] = {};
    int ia[4], ip[4];

    // ---- prologue: idx(0), stage tile0 -> buf0, idx(1) ----
#pragma unroll
    for (int r = 0; r < 4; ++r) {
        int nb = (f0 + (wv * 4 + r) * 4 + quad) * 9 + 0;
        ia[r] = neigh[nb]; ip[r] = ispad[nb];
    }
#pragma unroll
    for (int r = 0; r < 4; ++r) {
        int row = (wv * 4 + r) * 4 + quad;
        bool valid = (ip[r] == 0) && ((unsigned)ia[r] < 131072u);
        const char* src = valid ? (const char*)(cst + ((size_t)(ia[r] & 65535) << 7)) : zp;
        gl_lds16(src + ((l15 ^ (row & 15)) << 4), (char*)(&As[0][0]) + ((wv * 4 + r) << 10));
    }
#pragma unroll
    for (int r = 0; r < 4; ++r) {
        int nb = (f0 + (wv * 4 + r) * 4 + quad) * 9 + 1;
        ia[r] = neigh[nb]; ip[r] = ispad[nb];
    }

#pragma unroll
    for (int k = 0; k < 9; ++k) {
        // B fragments for this k — issued FIRST so consuming them in compute
        // does not FIFO-drain the k+1 gather prefetch.
        bf16x8 bfr[4][2];
#pragma unroll
        for (int s = 0; s < 4; ++s)
#pragma unroll
            for (int nt = 0; nt < 2; ++nt)
                bfr[s][nt] = *reinterpret_cast<const bf16x8*>(
                    w1ws + (((k * 16 + s * 4 + quad) * 128) + wv * 32 + nt * 16 + l15) * 8);
        asm volatile("" ::: "memory");
        __builtin_amdgcn_sched_barrier(0);

        // stage tile k+1 (gather, masked -> zeropage), swizzled source
        if (k < 8) {
#pragma unroll
            for (int r = 0; r < 4; ++r) {
                int row = (wv * 4 + r) * 4 + quad;
                bool valid = (ip[r] == 0) && ((unsigned)ia[r] < 131072u);
                const char* src = valid ? (const char*)(cst + ((size_t)(ia[r] & 65535) << 7)) : zp;
                gl_lds16(src + ((l15 ^ (row & 15)) << 4),
                         (char*)(&As[(k + 1) & 1][0]) + ((wv * 4 + r) << 10));
            }
        }
        // prefetch neighbor indices for tile k+2 (consumed next iteration -> wait is free)
        if (k < 7) {
#pragma unroll
            for (int r = 0; r < 4; ++r) {
                int nb = (f0 + (wv * 4 + r) * 4 + quad) * 9 + (k + 2);
                ia[r] = neigh[nb]; ip[r] = ispad[nb];
            }
        }
        // counted vmcnt: N = ops issued after tile-k's gathers (8 B + 4 gl_lds + 8 idx)
        if (k < 7)       asm volatile("s_waitcnt vmcnt(20)" ::: "memory");
        else if (k == 7) asm volatile("s_waitcnt vmcnt(12)" ::: "memory");
        else             asm volatile("s_waitcnt vmcnt(8)" ::: "memory");
        __builtin_amdgcn_s_barrier();
        __builtin_amdgcn_sched_barrier(0);

        // compute on As[k&1]
        const u16* Ab = &As[k & 1][0];
#pragma unroll
        for (int s = 0; s < 4; ++s) {
            bf16x8 af[4];
#pragma unroll
            for (int mt = 0; mt < 4; ++mt) {
                int face = mt * 16 + l15;
                int chunk = (s * 4 + quad) ^ l15;
                af[mt] = *reinterpret_cast<const bf16x8*>(&Ab[face * 128 + chunk * 8]);
            }
#pragma unroll
            for (int mt = 0; mt < 4; ++mt)
#pragma unroll
                for (int nt = 0; nt < 2; ++nt)
                    acc[mt][nt] = __builtin_amdgcn_mfma_f32_16x16x32_bf16(
                        af[mt], bfr[s][nt], acc[mt][nt], 0, 0, 0);
        }
        asm volatile("s_waitcnt lgkmcnt(0)" ::: "memory");
        __builtin_amdgcn_s_barrier();
        __builtin_amdgcn_sched_barrier(0);
    }

    // epilogue: + noise + bias1, lrelu(0.2)*sqrt(2), clip +-256, fp32 store
    float ns = nstr[0];
    float b1v[2];
    b1v[0] = bias1[wv * 32 + l15];
    b1v[1] = bias1[wv * 32 + 16 + l15];
#pragma unroll
    for (int mt = 0; mt < 4; ++mt) {
#pragma unroll
        for (int r = 0; r < 4; ++r) {
            int face = f0 + mt * 16 + quad * 4 + r;
            float nz = noise_c[face & 65535] * ns;
#pragma unroll
            for (int nt = 0; nt < 2; ++nt) {
                float v = acc[mt][nt][r] + nz + b1v[nt];
                v = (v > 0.f) ? v : 0.2f * v;
                v *= 1.41421356f;
                v = fminf(fmaxf(v, -256.f), 256.f);
                out[(size_t)face * 128 + wv * 32 + nt * 16 + l15] = v;
            }
        }
    }
}

// ---------------- kernel 2: conv2 (k=1 gather) + bias + clip ----------------
__global__ __launch_bounds__(256) void k2_img(
    const int* __restrict__ neigh, const int* __restrict__ ispad,
    const float* __restrict__ w2f, const float* __restrict__ bias2,
    const float* __restrict__ xbuf, float* __restrict__ imgout)
{
    __shared__ float ws2[768];
    int tid = threadIdx.x;
    ws2[tid] = w2f[tid];
    ws2[tid + 256] = w2f[tid + 256];
    ws2[tid + 512] = w2f[tid + 512];
    __syncthreads();
    int wv = tid >> 6, lane = tid & 63;
    int g = lane >> 4, sub = lane & 15;
    int face = blockIdx.x * 16 + wv * 4 + g;
    int b = face >> 16;
    int idx = neigh[face * 9];
    bool valid = (ispad[face * 9] == 0) && ((unsigned)idx < 131072u);
    float a0 = 0.f, a1 = 0.f, a2 = 0.f;
    if (valid) {
        float4 d0 = *(const float4*)(xbuf + (size_t)idx * 128 + sub * 8);
        float4 d1 = *(const float4*)(xbuf + (size_t)idx * 128 + sub * 8 + 4);
        float f[8] = {d0.x, d0.y, d0.z, d0.w, d1.x, d1.y, d1.z, d1.w};
        const float* w0 = &ws2[(b * 3 + 0) * 128 + sub * 8];
        const float* w1 = &ws2[(b * 3 + 1) * 128 + sub * 8];
        const float* w2p = &ws2[(b * 3 + 2) * 128 + sub * 8];
#pragma unroll
        for (int j = 0; j < 8; ++j) {
            a0 += f[j] * w0[j];
            a1 += f[j] * w1[j];
            a2 += f[j] * w2p[j];
        }
    }
#pragma unroll
    for (int d = 1; d < 16; d <<= 1) {
        a0 += __shfl_xor(a0, d);
        a1 += __shfl_xor(a1, d);
        a2 += __shfl_xor(a2, d);
    }
    if (sub < 3) {
        float v = (sub == 0) ? a0 : (sub == 1) ? a1 : a2;
        v += bias2[sub];
        v = fminf(fmaxf(v, -256.f), 256.f);
        imgout[face * 3 + sub] = v;
    }
}

extern "C" void kernel_launch(void* const* d_in, const int* in_sizes, int n_in,
                              void* d_out, int out_size, void* d_ws, size_t ws_size,
                              hipStream_t stream) {
    const int* neigh = (const int*)d_in[0];
    const int* ispad = (const int*)d_in[1];
    const float* wsv = (const float*)d_in[2];
    const float* cst = (const float*)d_in[3];
    const float* a1W = (const float*)d_in[4];
    const float* a1b = (const float*)d_in[5];
    const float* w1g = (const float*)d_in[6];
    const float* noise_c = (const float*)d_in[7];
    const float* nstr = (const float*)d_in[8];
    const float* bias1 = (const float*)d_in[9];
    const float* a2W = (const float*)d_in[10];
    const float* a2b = (const float*)d_in[11];
    const float* w2 = (const float*)d_in[12];
    const float* bias2 = (const float*)d_in[13];
    float* out = (float*)d_out;
    unsigned char* wsb = (unsigned char*)d_ws;

    k0a_styles<<<128, 256, 0, stream>>>(wsv, a1W, a1b, a2W, a2b, wsb);
    k0f_fused<<<4353, 256, 0, stream>>>(cst, w1g, w2, wsb);
    k1_conv<<<2048, 256, 0, stream>>>(neigh, ispad, noise_c, nstr, bias1, wsb, out);
    k2_img<<<8192, 256, 0, stream>>>(neigh, ispad, (const float*)(wsb + WS_W2F), bias2,
                                     out, out + XELEMS);
}